// Round 1
// baseline (7199.118 us; speedup 1.0000x reference)
//
#include <hip/hip_runtime.h>
#include <math.h>

#define E_DIM 1024
#define HH 8
#define DH 128
#define BB 32
#define MM 1024
#define NTOK 32768
#define CELU_A 1.3f
#define GN_EPS 1e-5f
#define SCALE_F 0.08838834764831845f   // 1/sqrt(128)

// ---------------------------------------------------------------------------
// Tiled SGEMM: C[64 x 128] tile of X @ W^T (+bias).
// GN=true : epilogue = CELU(1.3) + GroupNorm over the 128-wide tile (== one
//           group), write to [B,H,M,D] layout (h = blockIdx.y).
// GN=false: bias only, write token-major [N, E].
// XBHMD   : X is in [B,H,M,D] layout (attention output) instead of [N, E].
// ---------------------------------------------------------------------------
template<bool GN, bool XBHMD>
__global__ __launch_bounds__(256)
void gemm_tile_kernel(const float* __restrict__ X,
                      const float* __restrict__ W,
                      const float* __restrict__ bias,
                      const float* __restrict__ gamma,
                      const float* __restrict__ beta,
                      float* __restrict__ out)
{
    extern __shared__ float smem[];
    float* Xs   = smem;               // [16][68]  k-major X tile (padded)
    float* Wt   = Xs + 16 * 68;       // [16][132] k-major W tile (padded)
    float* Ybuf = Wt + 16 * 132;      // [64][132] GN scratch (GN only)
    float* mu_s = Ybuf + 64 * 132;    // [64]
    float* rs_s = mu_s + 64;          // [64]

    const int tok0 = blockIdx.x * 64;
    const int col0 = blockIdx.y * 128;
    const int tid  = threadIdx.x;
    const int ty = tid >> 4, tx = tid & 15;
    const int i0 = ty * 4, j0 = tx * 8;   // 4 rows x 8 cols per thread

    float acc[4][8];
#pragma unroll
    for (int r = 0; r < 4; ++r)
#pragma unroll
        for (int c = 0; c < 8; ++c) acc[r][c] = 0.f;

    const int xrow = tid >> 2;          // 0..63
    const int xkq  = (tid & 3) * 4;     // 0,4,8,12

    for (int k0 = 0; k0 < E_DIM; k0 += 16) {
        // ---- stage X tile (64 rows x 16 k) ----
        float4 xv;
        if (XBHMD) {
            int n = tok0 + xrow, b = n >> 10, m = n & 1023;
            int k = k0 + xkq, h = k >> 7, d = k & 127;
            xv = *(const float4*)&X[(size_t)((b * HH + h) * MM + m) * DH + d];
        } else {
            xv = *(const float4*)&X[(size_t)(tok0 + xrow) * E_DIM + (k0 + xkq)];
        }
        Xs[(xkq + 0) * 68 + xrow] = xv.x;
        Xs[(xkq + 1) * 68 + xrow] = xv.y;
        Xs[(xkq + 2) * 68 + xrow] = xv.z;
        Xs[(xkq + 3) * 68 + xrow] = xv.w;
        // ---- stage W tile (128 cols x 16 k), transposed to k-major ----
#pragma unroll
        for (int p = 0; p < 2; ++p) {
            int q = tid + p * 256;
            int c = q >> 2, kq = (q & 3) * 4;
            float4 wv = *(const float4*)&W[(size_t)(col0 + c) * E_DIM + (k0 + kq)];
            Wt[(kq + 0) * 132 + c] = wv.x;
            Wt[(kq + 1) * 132 + c] = wv.y;
            Wt[(kq + 2) * 132 + c] = wv.z;
            Wt[(kq + 3) * 132 + c] = wv.w;
        }
        __syncthreads();
#pragma unroll
        for (int kk = 0; kk < 16; ++kk) {
            float4 a4 = *(float4*)&Xs[kk * 68 + i0];
            float4 b0 = *(float4*)&Wt[kk * 132 + j0];
            float4 b1 = *(float4*)&Wt[kk * 132 + j0 + 4];
            float a[4]  = {a4.x, a4.y, a4.z, a4.w};
            float bb[8] = {b0.x, b0.y, b0.z, b0.w, b1.x, b1.y, b1.z, b1.w};
#pragma unroll
            for (int r = 0; r < 4; ++r)
#pragma unroll
                for (int c = 0; c < 8; ++c)
                    acc[r][c] = fmaf(a[r], bb[c], acc[r][c]);
        }
        __syncthreads();
    }

    float bv[8];
#pragma unroll
    for (int c = 0; c < 8; ++c) bv[c] = bias[col0 + j0 + c];

    if (GN) {
        // CELU then stash tile in LDS for per-token stats (group == tile)
#pragma unroll
        for (int r = 0; r < 4; ++r)
#pragma unroll
            for (int c = 0; c < 8; ++c) {
                float x = acc[r][c] + bv[c];
                x = x > 0.f ? x : CELU_A * expm1f(x * (1.0f / CELU_A));
                acc[r][c] = x;
                Ybuf[(i0 + r) * 132 + j0 + c] = x;
            }
        __syncthreads();
        if (tid < 64) {
            float s = 0.f, ss = 0.f;
            for (int c = 0; c < 128; ++c) {
                float v = Ybuf[tid * 132 + c];
                s += v; ss += v * v;
            }
            float mu  = s * (1.f / 128.f);
            float var = ss * (1.f / 128.f) - mu * mu;   // biased, matches jnp.var
            mu_s[tid] = mu;
            rs_s[tid] = rsqrtf(var + GN_EPS);
        }
        __syncthreads();
        const int h = blockIdx.y;   // tile width 128 == head dim
        float gm[8], bt[8];
#pragma unroll
        for (int c = 0; c < 8; ++c) {
            gm[c] = gamma[col0 + j0 + c];
            bt[c] = beta[col0 + j0 + c];
        }
#pragma unroll
        for (int r = 0; r < 4; ++r) {
            int n = tok0 + i0 + r, b = n >> 10, m = n & 1023;
            float mu = mu_s[i0 + r], rs = rs_s[i0 + r];
            float v[8];
#pragma unroll
            for (int c = 0; c < 8; ++c)
                v[c] = (acc[r][c] - mu) * rs * gm[c] + bt[c];
            size_t base = (size_t)((b * HH + h) * MM + m) * DH + j0;
            *(float4*)&out[base]     = make_float4(v[0], v[1], v[2], v[3]);
            *(float4*)&out[base + 4] = make_float4(v[4], v[5], v[6], v[7]);
        }
    } else {
#pragma unroll
        for (int r = 0; r < 4; ++r) {
            int n = tok0 + i0 + r;
            float v[8];
#pragma unroll
            for (int c = 0; c < 8; ++c) v[c] = acc[r][c] + bv[c];
            size_t base = (size_t)n * E_DIM + col0 + j0;
            *(float4*)&out[base]     = make_float4(v[0], v[1], v[2], v[3]);
            *(float4*)&out[base + 4] = make_float4(v[4], v[5], v[6], v[7]);
        }
    }
}

// ---------------------------------------------------------------------------
// Flash-style attention. Block = one (b,h) x 64-row Q tile. K/V in 32-row
// tiles through LDS, online softmax, O in registers. Output overwrites the
// q buffer (each block writes exactly the rows only it read).
// ---------------------------------------------------------------------------
__global__ __launch_bounds__(256)
void attention_kernel(const float* __restrict__ qbuf,
                      const float* __restrict__ kbuf,
                      const float* __restrict__ vbuf,
                      const int*   __restrict__ mask,
                      float* __restrict__ obuf)
{
    __shared__ float Qs[64 * 132];
    __shared__ float KVs[32 * 132];
    __shared__ float Ss[64 * 33];
    __shared__ float mrow[64], lrow[64], arow[64];

    const int q0  = blockIdx.x * 64;
    const int bh  = blockIdx.y;
    const int b   = bh >> 3;
    const size_t slab = (size_t)bh * MM * DH;
    const int tid = threadIdx.x;
    const int ty = tid >> 3, tx = tid & 7;
    const int si = ty * 2;      // 2 rows per thread (S and O phases)
    const int sj = tx * 4;      // 4 score cols per thread
    const int od = tx * 16;     // 16 output cols per thread

#pragma unroll
    for (int p = 0; p < 8; ++p) {        // Q tile: 64x128 = 2048 float4
        int q = tid + p * 256;
        int r = q >> 5, d4 = (q & 31) * 4;
        *(float4*)&Qs[r * 132 + d4] =
            *(const float4*)&qbuf[slab + (size_t)(q0 + r) * DH + d4];
    }
    if (tid < 64) { mrow[tid] = -3.0e38f; lrow[tid] = 0.f; }

    float o[2][16];
#pragma unroll
    for (int r = 0; r < 2; ++r)
#pragma unroll
        for (int c = 0; c < 16; ++c) o[r][c] = 0.f;

    __syncthreads();

    for (int kt = 0; kt < 32; ++kt) {
        // ---- load K tile ----
#pragma unroll
        for (int p = 0; p < 4; ++p) {
            int q = tid + p * 256;
            int r = q >> 5, d4 = (q & 31) * 4;
            *(float4*)&KVs[r * 132 + d4] =
                *(const float4*)&kbuf[slab + (size_t)(kt * 32 + r) * DH + d4];
        }
        __syncthreads();

        // ---- S = scale * Q K^T, masked ----
        float s2[2][4] = {{0.f,0.f,0.f,0.f},{0.f,0.f,0.f,0.f}};
        for (int k = 0; k < 128; k += 4) {
            float4 qa0 = *(float4*)&Qs[(si + 0) * 132 + k];
            float4 qa1 = *(float4*)&Qs[(si + 1) * 132 + k];
#pragma unroll
            for (int c = 0; c < 4; ++c) {
                float4 kv = *(float4*)&KVs[(sj + c) * 132 + k];
                s2[0][c] += qa0.x*kv.x + qa0.y*kv.y + qa0.z*kv.z + qa0.w*kv.w;
                s2[1][c] += qa1.x*kv.x + qa1.y*kv.y + qa1.z*kv.z + qa1.w*kv.w;
            }
        }
#pragma unroll
        for (int c = 0; c < 4; ++c) {
            int kpos = kt * 32 + sj + c;
            int mk = mask[b * MM + kpos];
            float sv0 = s2[0][c] * SCALE_F;
            float sv1 = s2[1][c] * SCALE_F;
            if (mk == 0) { sv0 = -1e9f; sv1 = -1e9f; }
            Ss[(si + 0) * 33 + sj + c] = sv0;
            Ss[(si + 1) * 33 + sj + c] = sv1;
        }
        __syncthreads();

        // ---- V load (KVs free now) + online-softmax row update ----
#pragma unroll
        for (int p = 0; p < 4; ++p) {
            int q = tid + p * 256;
            int r = q >> 5, d4 = (q & 31) * 4;
            *(float4*)&KVs[r * 132 + d4] =
                *(const float4*)&vbuf[slab + (size_t)(kt * 32 + r) * DH + d4];
        }
        if (tid < 64) {
            int r = tid;
            float mo = mrow[r];
            float mx = mo;
            for (int j = 0; j < 32; ++j) mx = fmaxf(mx, Ss[r * 33 + j]);
            float al = expf(mo - mx);
            float lsum = 0.f;
            for (int j = 0; j < 32; ++j) {
                float pv = expf(Ss[r * 33 + j] - mx);
                Ss[r * 33 + j] = pv;
                lsum += pv;
            }
            mrow[r] = mx;
            lrow[r] = lrow[r] * al + lsum;
            arow[r] = al;
        }
        __syncthreads();

        // ---- O = O*alpha + P @ V ----
        float a0 = arow[si], a1 = arow[si + 1];
#pragma unroll
        for (int c = 0; c < 16; ++c) { o[0][c] *= a0; o[1][c] *= a1; }
        for (int j = 0; j < 32; ++j) {
            float p0 = Ss[(si + 0) * 33 + j];
            float p1 = Ss[(si + 1) * 33 + j];
#pragma unroll
            for (int c4 = 0; c4 < 16; c4 += 4) {
                float4 vv = *(float4*)&KVs[j * 132 + od + c4];
                o[0][c4 + 0] += p0 * vv.x; o[0][c4 + 1] += p0 * vv.y;
                o[0][c4 + 2] += p0 * vv.z; o[0][c4 + 3] += p0 * vv.w;
                o[1][c4 + 0] += p1 * vv.x; o[1][c4 + 1] += p1 * vv.y;
                o[1][c4 + 2] += p1 * vv.z; o[1][c4 + 3] += p1 * vv.w;
            }
        }
        __syncthreads();
    }

    float li0 = 1.f / lrow[si], li1 = 1.f / lrow[si + 1];
#pragma unroll
    for (int c = 0; c < 16; ++c) { o[0][c] *= li0; o[1][c] *= li1; }
#pragma unroll
    for (int r = 0; r < 2; ++r) {
        size_t base = slab + (size_t)(q0 + si + r) * DH + od;
#pragma unroll
        for (int c4 = 0; c4 < 16; c4 += 4) {
            *(float4*)&obuf[base + c4] =
                make_float4(o[r][c4], o[r][c4+1], o[r][c4+2], o[r][c4+3]);
        }
    }
}

// ---------------------------------------------------------------------------
extern "C" void kernel_launch(void* const* d_in, const int* in_sizes, int n_in,
                              void* d_out, int out_size, void* d_ws, size_t ws_size,
                              hipStream_t stream)
{
    const float* query  = (const float*)d_in[0];
    const float* key    = (const float*)d_in[1];
    const int*   mask   = (const int*)d_in[2];
    // d_in[3] = value1 (intentionally unused by the reference)
    const float* value2 = (const float*)d_in[4];
    const float* Wq = (const float*)d_in[5];
    const float* bq = (const float*)d_in[6];
    const float* gq = (const float*)d_in[7];
    const float* betaq = (const float*)d_in[8];
    const float* Wk = (const float*)d_in[9];
    const float* bk = (const float*)d_in[10];
    const float* gk = (const float*)d_in[11];
    const float* betak = (const float*)d_in[12];
    const float* Wv = (const float*)d_in[13];
    const float* bv = (const float*)d_in[14];
    const float* gv = (const float*)d_in[15];
    const float* betav = (const float*)d_in[16];
    const float* Wm = (const float*)d_in[17];
    const float* bm = (const float*)d_in[18];
    float* out = (float*)d_out;

    float* qbuf = (float*)d_ws;                       // [B,H,M,D] fp32
    float* kbuf = qbuf + (size_t)NTOK * E_DIM;
    float* vbuf = kbuf + (size_t)NTOK * E_DIM;        // total 402 MB of ws

    dim3 gg(NTOK / 64, E_DIM / 128);
    size_t sh_gn = (size_t)(16 * 68 + 16 * 132 + 64 * 132 + 128) * sizeof(float);
    size_t sh_ng = (size_t)(16 * 68 + 16 * 132) * sizeof(float);

    gemm_tile_kernel<true,  false><<<gg, 256, sh_gn, stream>>>(query,  Wq, bq, gq, betaq, qbuf);
    gemm_tile_kernel<true,  false><<<gg, 256, sh_gn, stream>>>(key,    Wk, bk, gk, betak, kbuf);
    gemm_tile_kernel<true,  false><<<gg, 256, sh_gn, stream>>>(value2, Wv, bv, gv, betav, vbuf);

    attention_kernel<<<dim3(MM / 64, BB * HH), 256, 0, stream>>>(qbuf, kbuf, vbuf, mask, qbuf);

    // final projection reads attention output (BHMD layout, overwritten qbuf)
    gemm_tile_kernel<false, true><<<gg, 256, sh_ng, stream>>>(qbuf, Wm, bm, nullptr, nullptr, out);
}

// Round 2
// 2309.447 us; speedup vs baseline: 3.1172x; 3.1172x over previous
//
#include <hip/hip_runtime.h>
#include <math.h>

#define E_DIM 1024
#define HH 8
#define DH 128
#define BB 32
#define MM 1024
#define NTOK 32768
#define CELU_A 1.3f
#define GN_EPS 1e-5f
#define SCALE_F 0.08838834764831845f   // 1/sqrt(128)

typedef unsigned short ushort_t;
typedef __attribute__((ext_vector_type(8))) short short8;
typedef __attribute__((ext_vector_type(4))) float f32x4;

#define MFMA16(a,b,c) __builtin_amdgcn_mfma_f32_16x16x32_bf16((a),(b),(c),0,0,0)

union U8 { short8 v; ushort_t u[8]; };

__device__ __forceinline__ ushort_t f2bf(float f) {
    unsigned u = __float_as_uint(f);
    u += 0x7fffu + ((u >> 16) & 1u);          // round-to-nearest-even
    return (ushort_t)(u >> 16);
}
__device__ __forceinline__ float bf2f(ushort_t h) {
    return __uint_as_float(((unsigned)h) << 16);
}

// ---------------------------------------------------------------------------
// Split-bf16 MFMA GEMM, C tile 128x128, 4 waves in 2x2, each wave 64x64.
// C = X @ W^T via 3-term split: Xhi*Whi + Xhi*Wlo + Xlo*Whi (fp32-accurate).
// MODE 0: epilogue bias+CELU+GroupNorm, write split-bf16 rows [hi128|lo128]
//         into [B,H,M,256] (q or k buffer). h = blockIdx.y.
// MODE 1: same epilogue, write split-bf16 TRANSPOSED into vhi/vlo [B,H,D,M].
// MODE 2: X is fp32 [B,H,M,D] (attention out), epilogue bias only,
//         write fp32 token-major [N,E].
// ---------------------------------------------------------------------------
struct alignas(16) TilesT {
    ushort_t xhi[128 * 40]; ushort_t xlo[128 * 40];
    ushort_t whi[128 * 40]; ushort_t wlo[128 * 40];
};
struct alignas(16) EpiT {
    float ybuf[128 * 132]; float mu[128]; float rs[128];
};
union SmemU { TilesT t; EpiT e; };

template<int MODE>
__global__ __launch_bounds__(256, 2)
void proj_kernel(const float* __restrict__ X, const float* __restrict__ W,
                 const float* __restrict__ bias, const float* __restrict__ gamma,
                 const float* __restrict__ beta,
                 ushort_t* __restrict__ out0, ushort_t* __restrict__ out1,
                 float* __restrict__ outf)
{
    __shared__ SmemU sm;

    const int tid  = threadIdx.x;
    const int w    = tid >> 6, lane = tid & 63;
    const int quad = lane >> 4, l16 = lane & 15;
    const int wr   = (w >> 1) * 64, wc = (w & 1) * 64;
    const int row0 = blockIdx.x * 128, col0 = blockIdx.y * 128;

    f32x4 Cf[4][4];
#pragma unroll
    for (int i = 0; i < 4; ++i)
#pragma unroll
        for (int j = 0; j < 4; ++j) Cf[i][j] = (f32x4){0.f, 0.f, 0.f, 0.f};

    const int srow = tid >> 1, hf = tid & 1;

    for (int k0 = 0; k0 < E_DIM; k0 += 32) {
        // ---- stage X (convert fp32 -> hi/lo bf16) ----
        {
            const float* xp;
            if constexpr (MODE == 2) {
                int n = row0 + srow, b = n >> 10, m = n & 1023;
                int e0 = k0 + hf * 16, h = e0 >> 7, d = e0 & 127;
                xp = X + (((size_t)(b * HH + h) * MM + m) * DH + d);
            } else {
                xp = X + ((size_t)(row0 + srow) * E_DIM + k0 + hf * 16);
            }
            float4 xq[4];
#pragma unroll
            for (int p = 0; p < 4; ++p) xq[p] = ((const float4*)xp)[p];
            U8 h0, h1, l0, l1;
            const float* xf = (const float*)xq;
#pragma unroll
            for (int i = 0; i < 8; ++i) {
                float a = xf[i], b2 = xf[i + 8];
                ushort_t ha = f2bf(a), hb = f2bf(b2);
                h0.u[i] = ha; l0.u[i] = f2bf(a - bf2f(ha));
                h1.u[i] = hb; l1.u[i] = f2bf(b2 - bf2f(hb));
            }
            *(short8*)&sm.t.xhi[srow * 40 + hf * 16 + 0] = h0.v;
            *(short8*)&sm.t.xhi[srow * 40 + hf * 16 + 8] = h1.v;
            *(short8*)&sm.t.xlo[srow * 40 + hf * 16 + 0] = l0.v;
            *(short8*)&sm.t.xlo[srow * 40 + hf * 16 + 8] = l1.v;
        }
        // ---- stage W (convert fp32 -> hi/lo bf16) ----
        {
            const float* wp = W + ((size_t)(col0 + srow) * E_DIM + k0 + hf * 16);
            float4 wq[4];
#pragma unroll
            for (int p = 0; p < 4; ++p) wq[p] = ((const float4*)wp)[p];
            U8 h0, h1, l0, l1;
            const float* wf = (const float*)wq;
#pragma unroll
            for (int i = 0; i < 8; ++i) {
                float a = wf[i], b2 = wf[i + 8];
                ushort_t ha = f2bf(a), hb = f2bf(b2);
                h0.u[i] = ha; l0.u[i] = f2bf(a - bf2f(ha));
                h1.u[i] = hb; l1.u[i] = f2bf(b2 - bf2f(hb));
            }
            *(short8*)&sm.t.whi[srow * 40 + hf * 16 + 0] = h0.v;
            *(short8*)&sm.t.whi[srow * 40 + hf * 16 + 8] = h1.v;
            *(short8*)&sm.t.wlo[srow * 40 + hf * 16 + 0] = l0.v;
            *(short8*)&sm.t.wlo[srow * 40 + hf * 16 + 8] = l1.v;
        }
        __syncthreads();
        // ---- compute: 16 frag loads, 48 MFMAs ----
        short8 a_hi[4], a_lo[4], b_hi[4], b_lo[4];
#pragma unroll
        for (int mt = 0; mt < 4; ++mt) {
            int r = wr + mt * 16 + l16;
            a_hi[mt] = *(const short8*)&sm.t.xhi[r * 40 + quad * 8];
            a_lo[mt] = *(const short8*)&sm.t.xlo[r * 40 + quad * 8];
        }
#pragma unroll
        for (int nt = 0; nt < 4; ++nt) {
            int r = wc + nt * 16 + l16;
            b_hi[nt] = *(const short8*)&sm.t.whi[r * 40 + quad * 8];
            b_lo[nt] = *(const short8*)&sm.t.wlo[r * 40 + quad * 8];
        }
#pragma unroll
        for (int mt = 0; mt < 4; ++mt)
#pragma unroll
            for (int nt = 0; nt < 4; ++nt) {
                f32x4 c = Cf[mt][nt];
                c = MFMA16(a_hi[mt], b_hi[nt], c);
                c = MFMA16(a_hi[mt], b_lo[nt], c);
                c = MFMA16(a_lo[mt], b_hi[nt], c);
                Cf[mt][nt] = c;
            }
        __syncthreads();
    }

    // ---- epilogue ----
    if constexpr (MODE == 2) {
#pragma unroll
        for (int mt = 0; mt < 4; ++mt)
#pragma unroll
            for (int nt = 0; nt < 4; ++nt) {
                int c = col0 + wc + nt * 16 + l16;
                float bv = bias[c];
#pragma unroll
                for (int reg = 0; reg < 4; ++reg) {
                    int r = row0 + wr + mt * 16 + quad * 4 + reg;
                    outf[(size_t)r * E_DIM + c] = Cf[mt][nt][reg] + bv;
                }
            }
    } else {
        __syncthreads();   // tiles dead; reuse LDS as ybuf
#pragma unroll
        for (int mt = 0; mt < 4; ++mt)
#pragma unroll
            for (int nt = 0; nt < 4; ++nt) {
                int c = wc + nt * 16 + l16;
                float bv = bias[col0 + c];
#pragma unroll
                for (int reg = 0; reg < 4; ++reg) {
                    int r = wr + mt * 16 + quad * 4 + reg;
                    float x = Cf[mt][nt][reg] + bv;
                    x = x > 0.f ? x : CELU_A * (__expf(x * (1.0f / CELU_A)) - 1.0f);
                    sm.e.ybuf[r * 132 + c] = x;
                }
            }
        __syncthreads();
        {   // GroupNorm stats: 2 threads/row, shfl combine
            int r = tid >> 1, off = (tid & 1) * 64;
            float s = 0.f, ss = 0.f;
            for (int i = 0; i < 64; i += 4) {
                float4 v = *(float4*)&sm.e.ybuf[r * 132 + off + i];
                s  += v.x + v.y + v.z + v.w;
                ss += v.x * v.x + v.y * v.y + v.z * v.z + v.w * v.w;
            }
            s  += __shfl_xor(s, 1);
            ss += __shfl_xor(ss, 1);
            float mu  = s * (1.f / 128.f);
            float var = ss * (1.f / 128.f) - mu * mu;
            sm.e.mu[r] = mu;
            sm.e.rs[r] = rsqrtf(var + GN_EPS);
        }
        __syncthreads();
        if constexpr (MODE == 0) {
            int r = tid >> 1, off = (tid & 1) * 64;
            int n = row0 + r, b = n >> 10, m = n & 1023, h = blockIdx.y;
            float mu = sm.e.mu[r], rs = sm.e.rs[r];
            ushort_t* orow = out0 + ((size_t)((b * HH + h) * MM + m)) * 256;
            for (int i0 = 0; i0 < 64; i0 += 8) {
                U8 ph, pl;
#pragma unroll
                for (int j = 0; j < 8; ++j) {
                    int c = off + i0 + j;
                    float y = (sm.e.ybuf[r * 132 + c] - mu) * rs * gamma[col0 + c] + beta[col0 + c];
                    ushort_t hh = f2bf(y);
                    ph.u[j] = hh; pl.u[j] = f2bf(y - bf2f(hh));
                }
                *(short8*)&orow[off + i0]       = ph.v;
                *(short8*)&orow[128 + off + i0] = pl.v;
            }
        } else {  // MODE 1: transposed V write
            int d = tid >> 1, off = (tid & 1) * 64;
            int b = row0 >> 10, m0 = row0 & 1023, h = blockIdx.y;
            float g = gamma[col0 + d], be = beta[col0 + d];
            size_t vbase = ((size_t)(b * HH + h) * DH + d) * MM + m0 + off;
            for (int i0 = 0; i0 < 64; i0 += 8) {
                U8 ph, pl;
#pragma unroll
                for (int j = 0; j < 8; ++j) {
                    int rl = off + i0 + j;
                    float y = (sm.e.ybuf[rl * 132 + d] - sm.e.mu[rl]) * sm.e.rs[rl] * g + be;
                    ushort_t hh = f2bf(y);
                    ph.u[j] = hh; pl.u[j] = f2bf(y - bf2f(hh));
                }
                *(short8*)&out0[vbase + i0] = ph.v;
                *(short8*)&out1[vbase + i0] = pl.v;
            }
        }
    }
}

// ---------------------------------------------------------------------------
// Flash attention, MFMA. Block = (b,h) x 64 Q rows, 4 waves (16 rows each).
// Q frags register-resident (split). K tiles 32 rows, V^T tiles from global.
// S = 3-term split QK^T; softmax via shfl quad-reduce; PV = 3-term split.
// O overwrites the q buffer rows this block owns.
// ---------------------------------------------------------------------------
__global__ __launch_bounds__(256, 2)
void attn_kernel(const ushort_t* __restrict__ qsp, const ushort_t* __restrict__ ksp,
                 const ushort_t* __restrict__ vhi_g, const ushort_t* __restrict__ vlo_g,
                 const int* __restrict__ mask, float* __restrict__ obuf)
{
    __shared__ __align__(16) ushort_t Ks_hi[32 * 136], Ks_lo[32 * 136];
    __shared__ __align__(16) ushort_t Vt_hi[128 * 40], Vt_lo[128 * 40];
    __shared__ float Ss[64 * 33];
    __shared__ __align__(16) ushort_t Phi_s[64 * 40], Plo_s[64 * 40];
    __shared__ __align__(16) int mask_s[1024];
    __shared__ float alpha_s[64], mrow[64], lrow[64];

    const int tid  = threadIdx.x;
    const int w    = tid >> 6, lane = tid & 63;
    const int quad = lane >> 4, l16 = lane & 15;
    const int q0 = blockIdx.x * 64, bh = blockIdx.y, b = bh >> 3;

    ((int4*)mask_s)[tid] = ((const int4*)(mask + (size_t)b * MM))[tid];
    if (tid < 64) { mrow[tid] = -3.0e38f; lrow[tid] = 0.f; }

    short8 qa_hi[4], qa_lo[4];
    {
        const ushort_t* qrow = qsp + ((size_t)bh * MM + q0 + w * 16 + l16) * 256;
#pragma unroll
        for (int kc = 0; kc < 4; ++kc) {
            qa_hi[kc] = *(const short8*)(qrow + kc * 32 + quad * 8);
            qa_lo[kc] = *(const short8*)(qrow + 128 + kc * 32 + quad * 8);
        }
    }
    f32x4 Of[8];
#pragma unroll
    for (int i = 0; i < 8; ++i) Of[i] = (f32x4){0.f, 0.f, 0.f, 0.f};
    __syncthreads();

    for (int kt = 0; kt < 32; ++kt) {
        // ---- stage K tile ----
        {
            int j = tid >> 3, seg = tid & 7;
            const ushort_t* kr = ksp + ((size_t)bh * MM + kt * 32 + j) * 256 + seg * 16;
            short8 h0 = *(const short8*)(kr);
            short8 h1 = *(const short8*)(kr + 8);
            short8 l0 = *(const short8*)(kr + 128);
            short8 l1 = *(const short8*)(kr + 136);
            *(short8*)&Ks_hi[j * 136 + seg * 16 + 0] = h0;
            *(short8*)&Ks_hi[j * 136 + seg * 16 + 8] = h1;
            *(short8*)&Ks_lo[j * 136 + seg * 16 + 0] = l0;
            *(short8*)&Ks_lo[j * 136 + seg * 16 + 8] = l1;
        }
        // ---- stage V^T tile ----
        {
            int d = tid >> 1, hf = tid & 1;
            size_t vb = ((size_t)bh * DH + d) * MM + kt * 32 + hf * 16;
            short8 v0 = *(const short8*)(vhi_g + vb);
            short8 v1 = *(const short8*)(vhi_g + vb + 8);
            short8 u0 = *(const short8*)(vlo_g + vb);
            short8 u1 = *(const short8*)(vlo_g + vb + 8);
            *(short8*)&Vt_hi[d * 40 + hf * 16 + 0] = v0;
            *(short8*)&Vt_hi[d * 40 + hf * 16 + 8] = v1;
            *(short8*)&Vt_lo[d * 40 + hf * 16 + 0] = u0;
            *(short8*)&Vt_lo[d * 40 + hf * 16 + 8] = u1;
        }
        __syncthreads();
        // ---- S = split QK^T ----
        f32x4 Sf[2];
        Sf[0] = (f32x4){0.f, 0.f, 0.f, 0.f};
        Sf[1] = (f32x4){0.f, 0.f, 0.f, 0.f};
#pragma unroll
        for (int kc = 0; kc < 4; ++kc) {
#pragma unroll
            for (int ct = 0; ct < 2; ++ct) {
                const short8 kbh = *(const short8*)&Ks_hi[(ct * 16 + l16) * 136 + kc * 32 + quad * 8];
                const short8 kbl = *(const short8*)&Ks_lo[(ct * 16 + l16) * 136 + kc * 32 + quad * 8];
                f32x4 c = Sf[ct];
                c = MFMA16(qa_hi[kc], kbh, c);
                c = MFMA16(qa_hi[kc], kbl, c);
                c = MFMA16(qa_lo[kc], kbh, c);
                Sf[ct] = c;
            }
        }
#pragma unroll
        for (int ct = 0; ct < 2; ++ct)
#pragma unroll
            for (int reg = 0; reg < 4; ++reg)
                Ss[(w * 16 + quad * 4 + reg) * 33 + ct * 16 + l16] = Sf[ct][reg];
        __syncthreads();
        // ---- online softmax (all 256 threads; 4 threads/row) ----
        {
            int r = tid >> 2, cb = (tid & 3) * 8;
            float sv[8];
            float pm = -3.0e38f;
#pragma unroll
            for (int c = 0; c < 8; ++c) {
                float s = Ss[r * 33 + cb + c] * SCALE_F;
                if (mask_s[kt * 32 + cb + c] == 0) s = -1e9f;
                sv[c] = s;
                pm = fmaxf(pm, s);
            }
            pm = fmaxf(pm, __shfl_xor(pm, 1));
            pm = fmaxf(pm, __shfl_xor(pm, 2));
            float mo = mrow[r];
            float mx = fmaxf(mo, pm);
            float al = __expf(mo - mx);
            float ps = 0.f;
            U8 ph, pl;
#pragma unroll
            for (int c = 0; c < 8; ++c) {
                float p = __expf(sv[c] - mx);
                ps += p;
                ushort_t hh = f2bf(p);
                ph.u[c] = hh;
                pl.u[c] = f2bf(p - bf2f(hh));
            }
            *(short8*)&Phi_s[r * 40 + cb] = ph.v;
            *(short8*)&Plo_s[r * 40 + cb] = pl.v;
            ps += __shfl_xor(ps, 1);
            ps += __shfl_xor(ps, 2);
            if ((tid & 3) == 0) {
                mrow[r] = mx;
                alpha_s[r] = al;
                lrow[r] = lrow[r] * al + ps;
            }
        }
        __syncthreads();
        // ---- O = O*alpha + split P@V ----
        {
            float ar[4];
#pragma unroll
            for (int reg = 0; reg < 4; ++reg) ar[reg] = alpha_s[w * 16 + quad * 4 + reg];
            const short8 pah = *(const short8*)&Phi_s[(w * 16 + l16) * 40 + quad * 8];
            const short8 pal = *(const short8*)&Plo_s[(w * 16 + l16) * 40 + quad * 8];
#pragma unroll
            for (int ct = 0; ct < 8; ++ct) {
                f32x4 c = Of[ct];
#pragma unroll
                for (int reg = 0; reg < 4; ++reg) c[reg] *= ar[reg];
                const short8 vbh = *(const short8*)&Vt_hi[(ct * 16 + l16) * 40 + quad * 8];
                const short8 vbl = *(const short8*)&Vt_lo[(ct * 16 + l16) * 40 + quad * 8];
                c = MFMA16(pah, vbh, c);
                c = MFMA16(pah, vbl, c);
                c = MFMA16(pal, vbh, c);
                Of[ct] = c;
            }
        }
        __syncthreads();
    }
    // ---- epilogue: O/l, overwrite q rows (fp32) ----
    {
        float li[4];
#pragma unroll
        for (int reg = 0; reg < 4; ++reg) li[reg] = 1.f / lrow[w * 16 + quad * 4 + reg];
#pragma unroll
        for (int ct = 0; ct < 8; ++ct)
#pragma unroll
            for (int reg = 0; reg < 4; ++reg)
                obuf[((size_t)bh * MM + q0 + w * 16 + quad * 4 + reg) * DH + ct * 16 + l16] =
                    Of[ct][reg] * li[reg];
    }
}

// ---------------------------------------------------------------------------
extern "C" void kernel_launch(void* const* d_in, const int* in_sizes, int n_in,
                              void* d_out, int out_size, void* d_ws, size_t ws_size,
                              hipStream_t stream)
{
    const float* query  = (const float*)d_in[0];
    const float* key    = (const float*)d_in[1];
    const int*   mask   = (const int*)d_in[2];
    // d_in[3] = value1 (unused by reference)
    const float* value2 = (const float*)d_in[4];
    const float* Wq = (const float*)d_in[5];
    const float* bq = (const float*)d_in[6];
    const float* gq = (const float*)d_in[7];
    const float* betaq = (const float*)d_in[8];
    const float* Wk = (const float*)d_in[9];
    const float* bk = (const float*)d_in[10];
    const float* gk = (const float*)d_in[11];
    const float* betak = (const float*)d_in[12];
    const float* Wv = (const float*)d_in[13];
    const float* bv = (const float*)d_in[14];
    const float* gv = (const float*)d_in[15];
    const float* betav = (const float*)d_in[16];
    const float* Wm = (const float*)d_in[17];
    const float* bm = (const float*)d_in[18];
    float* out = (float*)d_out;

    // ws layout (ushort units), total 402,653,184 bytes (same as round 1):
    ushort_t* qsp = (ushort_t*)d_ws;                       // [B,H,M, hi128|lo128]  134MB
    ushort_t* ksp = qsp + (size_t)67108864;                // same                  134MB
    ushort_t* vhi = ksp + (size_t)67108864;                // [B,H,D,M]             67MB
    ushort_t* vlo = vhi + (size_t)33554432;                // [B,H,D,M]             67MB

    dim3 gproj(NTOK / 128, E_DIM / 128);   // (256, 8)

    proj_kernel<0><<<gproj, 256, 0, stream>>>(query,  Wq, bq, gq, betaq, qsp, nullptr, nullptr);
    proj_kernel<0><<<gproj, 256, 0, stream>>>(key,    Wk, bk, gk, betak, ksp, nullptr, nullptr);
    proj_kernel<1><<<gproj, 256, 0, stream>>>(value2, Wv, bv, gv, betav, vhi, vlo, nullptr);

    attn_kernel<<<dim3(MM / 64, BB * HH), 256, 0, stream>>>(qsp, ksp, vhi, vlo, mask, (float*)qsp);

    proj_kernel<2><<<gproj, 256, 0, stream>>>((const float*)qsp, Wm, bm, nullptr, nullptr,
                                              nullptr, nullptr, out);
}